// Round 3
// baseline (310.325 us; speedup 1.0000x reference)
//
#include <hip/hip_runtime.h>

// PositionId gather: out[t, :] = buffer[t - offsets[seg(t)], :]
// buffer: [8192, 1024] fp32 (32 MB), offsets: [BATCH+1] int32, out: [65536, 1024] fp32 (256 MB).

#define D_MODEL 1024
#define V4_PER_ROW (D_MODEL / 4)      // 256 float4 per row
#define ROWS_PER_BLOCK 32
#define THREADS 256
#define MAX_OFF 64

typedef float f32x4 __attribute__((ext_vector_type(4)));  // builtin-compatible vec4

__global__ __launch_bounds__(THREADS) void positionid_gather(
    const f32x4* __restrict__ buf,       // [MAX_SEQLEN, 256]
    const int*   __restrict__ offsets,   // [n_off]
    int n_off,
    f32x4*       __restrict__ out,       // [T, 256]
    int T)
{
    __shared__ int s_off[MAX_OFF];
    if (threadIdx.x < n_off) s_off[threadIdx.x] = offsets[threadIdx.x];
    __syncthreads();

    const int r0  = blockIdx.x * ROWS_PER_BLOCK;
    const int tid = threadIdx.x;

    // Initial segment for r0 via LDS scan (broadcast reads, no conflicts).
    int seg = 0;
    for (int i = 1; i < n_off - 1; ++i)
        if (s_off[i] <= r0) seg = i;
    int nxt = s_off[seg + 1];

    #pragma unroll
    for (int rb = 0; rb < ROWS_PER_BLOCK; rb += 4) {
        int pos[4];
        #pragma unroll
        for (int j = 0; j < 4; ++j) {
            int t = r0 + rb + j;
            while (t >= nxt && seg < n_off - 2) { ++seg; nxt = s_off[seg + 1]; }
            pos[j] = t - s_off[seg];
        }
        f32x4 v[4];
        #pragma unroll
        for (int j = 0; j < 4; ++j)
            v[j] = buf[(size_t)pos[j] * V4_PER_ROW + tid];
        #pragma unroll
        for (int j = 0; j < 4; ++j) {
            int t = r0 + rb + j;
            __builtin_nontemporal_store(v[j], &out[(size_t)t * V4_PER_ROW + tid]);
        }
    }
}

extern "C" void kernel_launch(void* const* d_in, const int* in_sizes, int n_in,
                              void* d_out, int out_size, void* d_ws, size_t ws_size,
                              hipStream_t stream) {
    const f32x4* buf     = (const f32x4*)d_in[0];
    const int*   offsets = (const int*)d_in[1];
    const int    n_off   = in_sizes[1];           // BATCH+1 = 17
    f32x4*       out     = (f32x4*)d_out;

    const int T = out_size / D_MODEL;             // 65536 rows
    const int grid = (T + ROWS_PER_BLOCK - 1) / ROWS_PER_BLOCK;  // 2048 blocks

    positionid_gather<<<dim3(grid), dim3(THREADS), 0, stream>>>(buf, offsets, n_off, out, T);
}